// Round 7
// baseline (285.335 us; speedup 1.0000x reference)
//
#include <hip/hip_runtime.h>

#define N_NODES 50000
#define E_EDGES 800000
#define D_INF   128
#define D_HIDF  512
#define D_OUTF  128
#define SCAN_NB ((N_NODES + 255) / 256)   // 196
#define GBLKS   196                       // gram blocks, 256 rows each
#define FBLKS   ((N_NODES + 63) / 64)     // 782 row-blocks fused kernel (64-row tiles)
#define EQ8     (E_EDGES / 8)             // 100,000 edges per ILP slot

// merged prep kernel block ranges: hist FIRST (long pole), then cast, then W
#define HIST_NB  ((EQ8 + 255) / 256)      // 391
#define CAST_NB  3125                     // N*128/8 / 256
#define PREPW_NB 256                      // 65536 / 256 (each of W1, W2)
#define PREP_ALL_NB (HIST_NB + CAST_NB + 2 * PREPW_NB)

typedef unsigned short u16;
typedef __attribute__((ext_vector_type(8))) short short8;
typedef __attribute__((ext_vector_type(4))) float floatx4;
typedef const __attribute__((address_space(1))) void gas_t;
typedef __attribute__((address_space(3))) void las_t;

__device__ __forceinline__ u16 f2bf(float f) {
    union { float f; unsigned u; } v; v.f = f;
    unsigned r = (v.u + 0x7fffu + ((v.u >> 16) & 1u)) >> 16;
    return (u16)r;
}
__device__ __forceinline__ float bf2f(u16 b) {
    union { unsigned u; float f; } v; v.u = ((unsigned)b) << 16; return v.f;
}

// ---------------- merged prep: hist | cast v->bf16 | W1^T | W2^T ----------------
__global__ __launch_bounds__(256) void prep_all_kernel(
        const float* __restrict__ v, const float* __restrict__ W1,
        const float* __restrict__ W2, const int* __restrict__ dst,
        u16* __restrict__ vbf, u16* __restrict__ W1t, u16* __restrict__ W2t,
        int* __restrict__ counts, int* __restrict__ pos) {
    int b = blockIdx.x;
    int tid = threadIdx.x;
    if (b < HIST_NB) {
        int t = b * 256 + tid;
        if (t >= EQ8) return;
        int d[8], p[8];
#pragma unroll
        for (int k = 0; k < 8; ++k) d[k] = dst[t + k * EQ8];
#pragma unroll
        for (int k = 0; k < 8; ++k) p[k] = atomicAdd(&counts[d[k]], 1);
#pragma unroll
        for (int k = 0; k < 8; ++k) pos[t + k * EQ8] = p[k];
    } else if (b < HIST_NB + CAST_NB) {
        int i = (b - HIST_NB) * 256 + tid;
        const float4 a = ((const float4*)v)[i * 2];
        const float4 c = ((const float4*)v)[i * 2 + 1];
        u16 o[8];
        o[0] = f2bf(a.x); o[1] = f2bf(a.y); o[2] = f2bf(a.z); o[3] = f2bf(a.w);
        o[4] = f2bf(c.x); o[5] = f2bf(c.y); o[6] = f2bf(c.z); o[7] = f2bf(c.w);
        ((float4*)vbf)[i] = *(const float4*)o;
    } else if (b < HIST_NB + CAST_NB + PREPW_NB) {
        int idx = (b - HIST_NB - CAST_NB) * 256 + tid;           // W1 [128][512]
        int k1 = idx >> 9, n1 = idx & 511;
        W1t[n1 * 128 + k1] = f2bf(W1[idx]);
    } else {
        int idx = (b - HIST_NB - CAST_NB - PREPW_NB) * 256 + tid; // W2 [512][128]
        int k2 = idx >> 7, n2 = idx & 127;
        W2t[n2 * 512 + k2] = f2bf(W2[idx]);
    }
}

// ---------------- scan phase 1: per-block sums ----------------
__global__ __launch_bounds__(256) void reduce_kernel(const int* __restrict__ counts,
                                                     int* __restrict__ block_sums) {
    __shared__ int lsum[4];
    int tid = threadIdx.x;
    int gid = blockIdx.x * 256 + tid;
    int s = (gid < N_NODES) ? counts[gid] : 0;
#pragma unroll
    for (int off = 32; off; off >>= 1) s += __shfl_down(s, off);
    if ((tid & 63) == 0) lsum[tid >> 6] = s;
    __syncthreads();
    if (tid == 0) block_sums[blockIdx.x] = lsum[0] + lsum[1] + lsum[2] + lsum[3];
}

// ---------------- scan phase 2 (merged) ----------------
__global__ __launch_bounds__(256) void scan_final(const int* __restrict__ counts,
                                                  const int* __restrict__ block_sums,
                                                  int* __restrict__ row_start) {
    __shared__ int sh[256];
    __shared__ int bs[256];
    int tid = threadIdx.x;
    int gid = blockIdx.x * 256 + tid;
    sh[tid] = (gid < N_NODES) ? counts[gid] : 0;
    bs[tid] = (tid < SCAN_NB) ? block_sums[tid] : 0;
    __syncthreads();
    for (int off = 1; off < 256; off <<= 1) {
        int t1 = (tid >= off) ? sh[tid - off] : 0;
        int t2 = (tid >= off) ? bs[tid - off] : 0;
        __syncthreads();
        sh[tid] += t1;
        bs[tid] += t2;
        __syncthreads();
    }
    int boff = (blockIdx.x == 0) ? 0 : bs[blockIdx.x - 1];
    int excl = (tid == 0) ? 0 : sh[tid - 1];
    if (gid < N_NODES) row_start[gid] = boff + excl;
    if (gid == 0) row_start[N_NODES] = E_EDGES;
}

// ---------------- CSR fill — no atomics ----------------
__global__ void fill_kernel(const int* __restrict__ src, const int* __restrict__ dst,
                            const float* __restrict__ w, const int* __restrict__ pos,
                            const int* __restrict__ row_start,
                            int2* __restrict__ csr_ew) {
    int e = blockIdx.x * blockDim.x + threadIdx.x;
    if (e >= E_EDGES) return;
    int d = dst[e];
    int idx = row_start[d] + pos[e];
    int2 rec;
    rec.x = src[e];
    rec.y = __float_as_int(w[e]);
    csr_ew[idx] = rec;
}

// ---------------- gather: 16 lanes/node, 2-edge unroll ----------------
__global__ __launch_bounds__(256) void gather_kernel(const u16* __restrict__ vbf,
                                                     const int* __restrict__ row_start,
                                                     const int2* __restrict__ csr_ew,
                                                     const float* __restrict__ eps_p,
                                                     u16* __restrict__ vagg) {
    int node = blockIdx.x * 16 + (threadIdx.x >> 4);
    if (node >= N_NODES) return;
    int c8 = (threadIdx.x & 15) << 3;
    int beg = row_start[node];
    int end = row_start[node + 1];
    float a[8] = {};
    int j = beg;
    for (; j + 1 < end; j += 2) {
        int2 e0 = csr_ew[j];
        int2 e1 = csr_ew[j + 1];
        float w0 = __int_as_float(e0.y);
        float w1 = __int_as_float(e1.y);
        float4 r0 = *(const float4*)(vbf + (size_t)e0.x * D_INF + c8);
        float4 r1 = *(const float4*)(vbf + (size_t)e1.x * D_INF + c8);
        const u16* p0 = (const u16*)&r0;
        const u16* p1 = (const u16*)&r1;
#pragma unroll
        for (int t = 0; t < 8; ++t) a[t] += w0 * bf2f(p0[t]);
#pragma unroll
        for (int t = 0; t < 8; ++t) a[t] += w1 * bf2f(p1[t]);
    }
    if (j < end) {
        int2 e0 = csr_ew[j];
        float w0 = __int_as_float(e0.y);
        float4 r0 = *(const float4*)(vbf + (size_t)e0.x * D_INF + c8);
        const u16* p0 = (const u16*)&r0;
#pragma unroll
        for (int t = 0; t < 8; ++t) a[t] += w0 * bf2f(p0[t]);
    }
    float e = eps_p[0];
    float4 rn = *(const float4*)(vbf + (size_t)node * D_INF + c8);
    const u16* pn = (const u16*)&rn;
    u16 o[8];
#pragma unroll
    for (int t = 0; t < 8; ++t) o[t] = f2bf(a[t] + e * bf2f(pn[t]));
    *(float4*)(vagg + (size_t)node * D_INF + c8) = *(const float4*)o;
}

// ---------------- gram: per-block partial G = vagg^T vagg (128x128) + colsum ----------
// 196 blocks x 256 rows. Per 32-row chunk: stage vagg^T in LDS [128][40] u16
// (stride 40 -> 2-way bank aliasing on b128 reads = free), then 8 waves x 8
// MFMA tiles accumulate G. G symmetric -> row/col orientation-proof. Rows >= M
// contribute zeros. colsum accumulated in registers during staging.
__global__ __launch_bounds__(512) void gram_kernel(
        const u16* __restrict__ vagg,
        float* __restrict__ Gp, float* __restrict__ csp, int M) {
    __shared__ __align__(16) char smem[16384];   // max(128*40*2, 32*128*4)
    u16* vT = (u16*)smem;
    const int tid = threadIdx.x;
    const int wave = tid >> 6, lane = tid & 63;
    const int lm = lane & 15, quad = lane >> 4;
    const int bm = blockIdx.x * 256;
    const int r0 = tid >> 4;          // 0..31 chunk row
    const int c8 = tid & 15;          // col group
    floatx4 acc[8] = {};
    float csum[8] = {};
#pragma unroll
    for (int ck = 0; ck < 8; ++ck) {
        int grow = bm + ck * 32 + r0;
        float4 rv = make_float4(0.f, 0.f, 0.f, 0.f);
        if (grow < M) rv = *(const float4*)(vagg + (size_t)grow * 128 + c8 * 8);
        const u16* pv = (const u16*)&rv;
        __syncthreads();              // prev chunk's frag reads done
#pragma unroll
        for (int j = 0; j < 8; ++j) {
            vT[(c8 * 8 + j) * 40 + r0] = pv[j];
            csum[j] += bf2f(pv[j]);
        }
        __syncthreads();
        short8 af = *(const short8*)&vT[(wave * 16 + lm) * 40 + quad * 8];
#pragma unroll
        for (int tj = 0; tj < 8; ++tj) {
            short8 bf = *(const short8*)&vT[(tj * 16 + lm) * 40 + quad * 8];
            acc[tj] = __builtin_amdgcn_mfma_f32_16x16x32_bf16(af, bf, acc[tj], 0, 0, 0);
        }
    }
    __syncthreads();                  // last chunk reads done before smem reuse
    // G partials: tile (ti=wave, tj); C layout col=lane&15, row=quad*4+reg
#pragma unroll
    for (int tj = 0; tj < 8; ++tj)
#pragma unroll
        for (int r = 0; r < 4; ++r) {
            int gi = wave * 16 + quad * 4 + r;
            int gj = tj * 16 + lm;
            Gp[(size_t)blockIdx.x * 16384 + gi * 128 + gj] = acc[tj][r];
        }
    // colsum partial reduce across the 32 chunk-rows
    float* cred = (float*)smem;
#pragma unroll
    for (int j = 0; j < 8; ++j) cred[r0 * 128 + c8 * 8 + j] = csum[j];
    __syncthreads();
    if (tid < 128) {
        float s = 0.f;
#pragma unroll
        for (int r = 0; r < 32; ++r) s += cred[r * 128 + tid];
        csp[(size_t)blockIdx.x * 128 + tid] = s;
    }
}

// ---------------- gsum: reduce gram partials -> G[16384], colsum[128] ----------
__global__ __launch_bounds__(256) void gsum_kernel(
        const float* __restrict__ Gp, const float* __restrict__ csp,
        float* __restrict__ G, float* __restrict__ colsum) {
    int i = blockIdx.x * 256 + threadIdx.x;
    if (i < 16384) {
        float s = 0.f;
        for (int b = 0; b < GBLKS; ++b) s += Gp[(size_t)b * 16384 + i];
        G[i] = s;
    } else if (i < 16384 + 128) {
        int c = i - 16384;
        float s = 0.f;
        for (int b = 0; b < GBLKS; ++b) s += csp[(size_t)b * 128 + c];
        colsum[c] = s;
    }
}

// ---------------- BN1 finalize from Gram: per col c, q = w_c^T G w_c ----------
// x1 = vagg@W1 + b1:  m = colsum.w/N + b;  E[x^2] = (q + 2 b colsum.w)/N + b^2
__global__ __launch_bounds__(128) void bn1fin_gram(
        const float* __restrict__ G, const float* __restrict__ colsum,
        const u16* __restrict__ W1t, const float* __restrict__ b1,
        const float* __restrict__ g1, const float* __restrict__ be1,
        float* __restrict__ scale1, float* __restrict__ shift1) {
    __shared__ float red[4];
    const int c = blockIdx.x;
    const int i = threadIdx.x;
    float wi = bf2f(W1t[c * 128 + i]);
    float dot = 0.f;
    for (int j = 0; j < 128; ++j)                 // G symmetric: row j, lane i coalesced
        dot += G[j * 128 + i] * bf2f(W1t[c * 128 + j]);
    float qp = wi * dot;
    float sp = wi * colsum[i];
#pragma unroll
    for (int off = 32; off; off >>= 1) {
        qp += __shfl_down(qp, off);
        sp += __shfl_down(sp, off);
    }
    if ((i & 63) == 0) { red[(i >> 6) * 2] = qp; red[(i >> 6) * 2 + 1] = sp; }
    __syncthreads();
    if (i == 0) {
        float q = red[0] + red[2];
        float s = red[1] + red[3];
        float b = b1[c];
        const float inv_n = 1.0f / (float)N_NODES;
        float m = s * inv_n + b;
        float ex2 = (q + 2.f * b * s) * inv_n + b * b;
        float var = ex2 - m * m;
        float rs = rsqrtf(var + 1e-5f);
        float sc = g1[c] * rs;
        scale1[c] = sc;
        shift1[c] = be1[c] - sc * m;
    }
}

// ---------------- fused: GEMM1-recompute + BN1 + ReLU -> h(LDS) -> GEMM2 + BN2 partials ----
// 64 rows/block, 512 thr (8 waves = 2x4). LDS 80 KB -> 2 blocks/CU.
__global__ __launch_bounds__(512, 4) void fused_mlp(
        const u16* __restrict__ vagg, const u16* __restrict__ W1t,
        const u16* __restrict__ W2t,
        const float* __restrict__ b1, const float* __restrict__ scale1,
        const float* __restrict__ shift1, const float* __restrict__ b2,
        u16* __restrict__ x2, float* __restrict__ psum, float* __restrict__ psq,
        int M) {
    __shared__ __align__(16) char smem[81920];
    u16* As  = (u16*)smem;
    u16* W1s = (u16*)(smem + 16384);
    u16* W2s = (u16*)smem;
    u16* hs  = (u16*)(smem + 16384);
    const int bm = blockIdx.x * 64;
    const int tid = threadIdx.x;
    const int wave = tid >> 6, lane = tid & 63;
    const int wr = wave >> 2, wc = wave & 3;     // 2 row x 4 col wave groups
    const int wm = wr * 32;
    const int wn1 = wc * 128;                    // GEMM1 col span 128
    const int wn2 = wc * 32;                     // GEMM2 col span 32
    const int lm = lane & 15, quad = lane >> 4;

    floatx4 acc1[2][8] = {};
    floatx4 acc2[2][2] = {};

    auto stage_w1 = [&](int win) {               // [512][64]u16 = 64 KB, 8 rounds
#pragma unroll
        for (int u = 0; u < 8; ++u) {
            int c = tid + u * 512;
            int col = c >> 3, s = c & 7;
            __builtin_amdgcn_global_load_lds(
                (gas_t*)(W1t + (size_t)col * 128 + win * 64 + ((s ^ (col & 7)) * 8)),
                (las_t*)(W1s + col * 64 + s * 8), 16, 0, 0);
        }
    };
    auto stage_w2 = [&](int win) {               // [128][64]u16 = 16 KB, 2 rounds
#pragma unroll
        for (int u = 0; u < 2; ++u) {
            int c = tid + u * 512;
            int n = c >> 3, s = c & 7;
            __builtin_amdgcn_global_load_lds(
                (gas_t*)(W2t + (size_t)n * 512 + win * 64 + ((s ^ (n & 7)) * 8)),
                (las_t*)(W2s + n * 64 + s * 8), 16, 0, 0);
        }
    };
    auto compute1 = [&](int ks) {                // ks in 0..3; W1s window = ks>>1
        short8 a[2], b[8];
#pragma unroll
        for (int i = 0; i < 2; ++i) {
            int row = wm + i * 16 + lm;
            a[i] = *(const short8*)&As[row * 128 + (((ks * 4 + quad) ^ (row & 7)) * 8)];
        }
#pragma unroll
        for (int j = 0; j < 8; ++j) {
            int col = wn1 + j * 16 + lm;
            b[j] = *(const short8*)&W1s[col * 64 + ((((ks & 1) * 4 + quad) ^ (col & 7)) * 8)];
        }
#pragma unroll
        for (int i = 0; i < 2; ++i)
#pragma unroll
            for (int j = 0; j < 8; ++j)
                acc1[i][j] = __builtin_amdgcn_mfma_f32_16x16x32_bf16(a[i], b[j], acc1[i][j], 0, 0, 0);
    };
    auto compute2 = [&](int ks) {                // ks in 0..15; W2s window = ks>>1
        short8 a[2], b[2];
#pragma unroll
        for (int i = 0; i < 2; ++i) {
            int row = wm + i * 16 + lm;
            a[i] = *(const short8*)&hs[row * 512 + (((ks * 4 + quad) ^ (row & 7)) * 8)];
        }
#pragma unroll
        for (int j = 0; j < 2; ++j) {
            int n = wn2 + j * 16 + lm;
            b[j] = *(const short8*)&W2s[n * 64 + ((((ks & 1) * 4 + quad) ^ (n & 7)) * 8)];
        }
#pragma unroll
        for (int i = 0; i < 2; ++i)
#pragma unroll
            for (int j = 0; j < 2; ++j)
                acc2[i][j] = __builtin_amdgcn_mfma_f32_16x16x32_bf16(a[i], b[j], acc2[i][j], 0, 0, 0);
    };

    // ---- stage vagg tile [64][128] + W1 window 0 ----
#pragma unroll
    for (int u = 0; u < 2; ++u) {
        int c = tid + u * 512;
        int row = c >> 4, s = c & 15;
        int grow = bm + row; if (grow > M - 1) grow = M - 1;
        __builtin_amdgcn_global_load_lds(
            (gas_t*)(vagg + (size_t)grow * 128 + ((s ^ (row & 7)) * 8)),
            (las_t*)(As + row * 128 + s * 8), 16, 0, 0);
    }
    stage_w1(0);
    __syncthreads();
    compute1(0); compute1(1);
    __syncthreads();
    stage_w1(1);
    __syncthreads();
    compute1(2); compute1(3);
    __syncthreads();                  // all reads of As / W1s done

    // ---- issue W2 window 0 early (into As region), then BN1+ReLU -> h ----
    stage_w2(0);
    {
        float hsc[8], hsh[8];
#pragma unroll
        for (int j = 0; j < 8; ++j) {
            int col = wn1 + j * 16 + lm;
            float sc = scale1[col];
            hsc[j] = sc;
            hsh[j] = shift1[col] + sc * b1[col];
        }
#pragma unroll
        for (int i = 0; i < 2; ++i)
#pragma unroll
            for (int j = 0; j < 8; ++j)
#pragma unroll
                for (int r = 0; r < 4; ++r) {
                    int row = wm + i * 16 + quad * 4 + r;
                    int col = wn1 + j * 16 + lm;
                    float hv = fmaxf(0.f, acc1[i][j][r] * hsc[j] + hsh[j]);
                    hs[row * 512 + (((col >> 3) ^ (row & 7)) * 8) + (col & 7)] = f2bf(hv);
                }
    }
    __syncthreads();                  // h visible + W2s(0) staged

    // ---- GEMM2: 8 windows x 2 ksteps ----
#pragma unroll
    for (int win = 0; win < 8; ++win) {
        compute2(win * 2); compute2(win * 2 + 1);
        __syncthreads();
        if (win < 7) { stage_w2(win + 1); __syncthreads(); }
    }

    // ---- BN2 partials ----
    float* redS = (float*)smem;
    float* redQ = redS + 128;
    if (tid < 128) { redS[tid] = 0.f; redQ[tid] = 0.f; }
    __syncthreads();
    float bj2[2];
#pragma unroll
    for (int j = 0; j < 2; ++j) {
        int cl = wn2 + j * 16 + lm;
        bj2[j] = b2[cl];
        float s = 0.f, q = 0.f;
#pragma unroll
        for (int i = 0; i < 2; ++i) {
            int row0 = bm + wm + i * 16 + quad * 4;
#pragma unroll
            for (int r = 0; r < 4; ++r)
                if (row0 + r < M) { float x = acc2[i][j][r] + bj2[j]; s += x; q += x * x; }
        }
        s += __shfl_xor(s, 16); q += __shfl_xor(q, 16);
        s += __shfl_xor(s, 32); q += __shfl_xor(q, 32);
        if (quad == 0) { atomicAdd(&redS[cl], s); atomicAdd(&redQ[cl], q); }
    }
    __syncthreads();
    if (tid < 128) {
        psum[(size_t)blockIdx.x * 128 + tid] = redS[tid];
        psq [(size_t)blockIdx.x * 128 + tid] = redQ[tid];
    }
    __syncthreads();                  // redS reads done before obuf overwrite

    // ---- coalesced bf16 x2 write via obuf [64][132] f32 ----
    float* obuf = (float*)smem;
#pragma unroll
    for (int i = 0; i < 2; ++i)
#pragma unroll
        for (int j = 0; j < 2; ++j)
#pragma unroll
            for (int r = 0; r < 4; ++r) {
                int row = wm + i * 16 + quad * 4 + r;
                int col = wn2 + j * 16 + lm;
                obuf[row * 132 + col] = acc2[i][j][r] + bj2[j];
            }
    __syncthreads();
    {
        int row = tid >> 3, seg = (tid & 7) * 16;
        int grow = bm + row;
        if (grow < M) {
            u16 ob[16];
#pragma unroll
            for (int t = 0; t < 4; ++t) {
                float4 f = *(float4*)&obuf[row * 132 + seg + t * 4];
                ob[t * 4 + 0] = f2bf(f.x);
                ob[t * 4 + 1] = f2bf(f.y);
                ob[t * 4 + 2] = f2bf(f.z);
                ob[t * 4 + 3] = f2bf(f.w);
            }
            u16* dp = x2 + (size_t)grow * 128 + seg;
            *(float4*)dp       = *(float4*)ob;
            *(float4*)(dp + 8) = *(float4*)(ob + 8);
        }
    }
}

// ---------------- BN finalize (parallel reduce of per-block partials) ----------------
__global__ __launch_bounds__(1024) void bn_finalize_kernel(
        const float* __restrict__ psum, const float* __restrict__ psq,
        const float* __restrict__ gamma, const float* __restrict__ beta,
        float* __restrict__ scale, float* __restrict__ shift,
        int nblocks, int Ncols, float inv_n) {
    __shared__ float shS[16][64];
    __shared__ float shQ[16][64];
    const int tx = threadIdx.x;
    const int ty = threadIdx.y;
    const int c = blockIdx.x * 64 + tx;
    float s = 0.f, q = 0.f;
    for (int b = ty; b < nblocks; b += 16) {
        s += psum[(size_t)b * Ncols + c];
        q += psq [(size_t)b * Ncols + c];
    }
    shS[ty][tx] = s;
    shQ[ty][tx] = q;
    __syncthreads();
    if (ty == 0) {
        float S = 0.f, Q = 0.f;
#pragma unroll
        for (int r = 0; r < 16; ++r) { S += shS[r][tx]; Q += shQ[r][tx]; }
        float m = S * inv_n;
        float var = Q * inv_n - m * m;
        float rs = rsqrtf(var + 1e-5f);
        float sc = gamma[c] * rs;
        scale[c] = sc;
        shift[c] = beta[c] - sc * m;
    }
}

// ---------------- BN2 apply + ReLU: x2 bf16 -> d_out fp32 ----------------
__global__ void bn2_apply_kernel(const u16* __restrict__ X, float* __restrict__ Y,
                                 const float* __restrict__ scale,
                                 const float* __restrict__ shift, int n8) {
    int i = blockIdx.x * blockDim.x + threadIdx.x;
    if (i >= n8) return;
    int c = (i & 15) << 3;
    float4 raw = ((const float4*)X)[i];
    const u16* xb = (const u16*)&raw;
    float4 sc0 = *(const float4*)(scale + c);
    float4 sc1 = *(const float4*)(scale + c + 4);
    float4 sh0 = *(const float4*)(shift + c);
    float4 sh1 = *(const float4*)(shift + c + 4);
    float4 y0, y1;
    y0.x = fmaxf(0.f, bf2f(xb[0]) * sc0.x + sh0.x);
    y0.y = fmaxf(0.f, bf2f(xb[1]) * sc0.y + sh0.y);
    y0.z = fmaxf(0.f, bf2f(xb[2]) * sc0.z + sh0.z);
    y0.w = fmaxf(0.f, bf2f(xb[3]) * sc0.w + sh0.w);
    y1.x = fmaxf(0.f, bf2f(xb[4]) * sc1.x + sh1.x);
    y1.y = fmaxf(0.f, bf2f(xb[5]) * sc1.y + sh1.y);
    y1.z = fmaxf(0.f, bf2f(xb[6]) * sc1.z + sh1.z);
    y1.w = fmaxf(0.f, bf2f(xb[7]) * sc1.w + sh1.w);
    ((float4*)Y)[i * 2]     = y0;
    ((float4*)Y)[i * 2 + 1] = y1;
}

extern "C" void kernel_launch(void* const* d_in, const int* in_sizes, int n_in,
                              void* d_out, int out_size, void* d_ws, size_t ws_size,
                              hipStream_t stream) {
    const float* v    = (const float*)d_in[0];
    const int* src    = (const int*)d_in[1];
    const int* dst    = (const int*)d_in[2];
    const float* ew   = (const float*)d_in[3];
    const float* eps  = (const float*)d_in[4];
    const float* W1   = (const float*)d_in[5];
    const float* b1   = (const float*)d_in[6];
    const float* g1   = (const float*)d_in[7];
    const float* be1  = (const float*)d_in[8];
    const float* W2   = (const float*)d_in[9];
    const float* b2   = (const float*)d_in[10];
    const float* g2   = (const float*)d_in[11];
    const float* be2  = (const float*)d_in[12];
    float* out = (float*)d_out;

    // ---- workspace layout (bytes) ----
    char* base = (char*)d_ws;
    // [0, 51.2 MB): gram scratch (x1 no longer materialized)
    float* Gp     = (float*)(base);                  // [196][16384] f32 = 12.85 MB
    float* csp    = (float*)(base + 13000000ull);    // [196][128] f32
    float* G      = (float*)(base + 13200000ull);    // [16384] f32
    float* colsum = (float*)(base + 13300000ull);    // [128] f32
    u16* vbf  = (u16*)(base + 51200000ull);        // [N,128] bf16
    u16* vagg = (u16*)(base + 64000000ull);        // [N,128] bf16
    u16* x2   = (u16*)(base + 76800000ull);        // [N,128] bf16 raw pre-BN2
    u16* W1t  = (u16*)(base + 89600000ull);        // 512x128 bf16
    u16* W2t  = (u16*)(base + 89731072ull);        // 128x512 bf16
    float* psum   = (float*)(base + 89862144ull);  // [782][128] fp32 (BN2)
    float* psq    = (float*)(base + 90663168ull);  // same
    float* scale1 = (float*)(base + 91464192ull);  // 512
    float* shift1 = scale1 + 512;
    float* scale2 = shift1 + 512;
    float* shift2 = scale2 + 128;
    int* counts     = (int*)(shift2 + 128);        // 50,000
    int* row_start  = counts + 50000;              // 50,001 (+pad 3)
    int* pos        = row_start + 50004;           // 800,000
    int2* csr_ew    = (int2*)(pos + 800000);       // 800,000 * 8 B
    int* block_sums = (int*)(csr_ew + 800000);     // 256

    hipMemsetAsync(counts, 0, (size_t)50000 * sizeof(int), stream);

    // merged prep (hist first | cast | W1^T | W2^T) + CSR build + gather
    prep_all_kernel<<<PREP_ALL_NB, 256, 0, stream>>>(v, W1, W2, dst, vbf, W1t, W2t,
                                                     counts, pos);
    reduce_kernel<<<SCAN_NB, 256, 0, stream>>>(counts, block_sums);
    scan_final<<<SCAN_NB, 256, 0, stream>>>(counts, block_sums, row_start);
    fill_kernel<<<(E_EDGES + 255) / 256, 256, 0, stream>>>(src, dst, ew, pos, row_start, csr_ew);
    gather_kernel<<<(N_NODES + 15) / 16, 256, 0, stream>>>(vbf, row_start, csr_ew, eps, vagg);

    // BN1 stats via Gram matrix: G = vagg^T vagg (128x128), colsum = 1^T vagg
    gram_kernel<<<GBLKS, 512, 0, stream>>>(vagg, Gp, csp, N_NODES);
    gsum_kernel<<<(16384 + 128 + 255) / 256, 256, 0, stream>>>(Gp, csp, G, colsum);
    bn1fin_gram<<<D_HIDF, 128, 0, stream>>>(G, colsum, W1t, b1, g1, be1, scale1, shift1);

    // fused recompute-GEMM1 + BN1 + ReLU (h in LDS) + GEMM2 + BN2 partials
    fused_mlp<<<FBLKS, 512, 0, stream>>>(vagg, W1t, W2t, b1, scale1, shift1, b2,
                                         x2, psum, psq, N_NODES);
    bn_finalize_kernel<<<D_OUTF / 64, dim3(64, 16), 0, stream>>>(
        psum, psq, g2, be2, scale2, shift2, FBLKS, D_OUTF, 1.0f / N_NODES);

    // BN2 apply + ReLU: x2 (bf16) -> d_out (fp32)
    {
        int n8 = N_NODES * D_OUTF / 8;
        bn2_apply_kernel<<<(n8 + 255) / 256, 256, 0, stream>>>(x2, out, scale2, shift2, n8);
    }
}

// Round 8
// 269.174 us; speedup vs baseline: 1.0600x; 1.0600x over previous
//
#include <hip/hip_runtime.h>

#define N_NODES 50000
#define E_EDGES 800000
#define D_INF   128
#define D_HIDF  512
#define D_OUTF  128
#define SCAN_NB ((N_NODES + 255) / 256)   // 196
#define M1BLKS  ((N_NODES + 255) / 256)   // 196 row-blocks stats GEMM1 (256-row tiles)
#define FBLKS   ((N_NODES + 63) / 64)     // 782 row-blocks fused kernel (64-row tiles)
#define EQ8     (E_EDGES / 8)             // 100,000 edges per ILP slot

// merged prep kernel block ranges: hist FIRST (long pole), then cast, then W
#define HIST_NB  ((EQ8 + 255) / 256)      // 391
#define CAST_NB  3125                     // N*128/8 / 256
#define PREPW_NB 256                      // 65536 / 256 (each of W1, W2)
#define PREP_ALL_NB (HIST_NB + CAST_NB + 2 * PREPW_NB)

typedef unsigned short u16;
typedef __attribute__((ext_vector_type(8))) short short8;
typedef __attribute__((ext_vector_type(4))) float floatx4;
typedef const __attribute__((address_space(1))) void gas_t;
typedef __attribute__((address_space(3))) void las_t;

__device__ __forceinline__ u16 f2bf(float f) {
    union { float f; unsigned u; } v; v.f = f;
    unsigned r = (v.u + 0x7fffu + ((v.u >> 16) & 1u)) >> 16;
    return (u16)r;
}
__device__ __forceinline__ float bf2f(u16 b) {
    union { unsigned u; float f; } v; v.u = ((unsigned)b) << 16; return v.f;
}

// ---------------- merged prep: hist | cast v->bf16 | W1^T | W2^T ----------------
__global__ __launch_bounds__(256) void prep_all_kernel(
        const float* __restrict__ v, const float* __restrict__ W1,
        const float* __restrict__ W2, const int* __restrict__ dst,
        u16* __restrict__ vbf, u16* __restrict__ W1t, u16* __restrict__ W2t,
        int* __restrict__ counts, int* __restrict__ pos) {
    int b = blockIdx.x;
    int tid = threadIdx.x;
    if (b < HIST_NB) {
        int t = b * 256 + tid;
        if (t >= EQ8) return;
        int d[8], p[8];
#pragma unroll
        for (int k = 0; k < 8; ++k) d[k] = dst[t + k * EQ8];
#pragma unroll
        for (int k = 0; k < 8; ++k) p[k] = atomicAdd(&counts[d[k]], 1);
#pragma unroll
        for (int k = 0; k < 8; ++k) pos[t + k * EQ8] = p[k];
    } else if (b < HIST_NB + CAST_NB) {
        int i = (b - HIST_NB) * 256 + tid;
        const float4 a = ((const float4*)v)[i * 2];
        const float4 c = ((const float4*)v)[i * 2 + 1];
        u16 o[8];
        o[0] = f2bf(a.x); o[1] = f2bf(a.y); o[2] = f2bf(a.z); o[3] = f2bf(a.w);
        o[4] = f2bf(c.x); o[5] = f2bf(c.y); o[6] = f2bf(c.z); o[7] = f2bf(c.w);
        ((float4*)vbf)[i] = *(const float4*)o;
    } else if (b < HIST_NB + CAST_NB + PREPW_NB) {
        int idx = (b - HIST_NB - CAST_NB) * 256 + tid;           // W1 [128][512]
        int k1 = idx >> 9, n1 = idx & 511;
        W1t[n1 * 128 + k1] = f2bf(W1[idx]);
    } else {
        int idx = (b - HIST_NB - CAST_NB - PREPW_NB) * 256 + tid; // W2 [512][128]
        int k2 = idx >> 7, n2 = idx & 127;
        W2t[n2 * 512 + k2] = f2bf(W2[idx]);
    }
}

// ---------------- scan phase 1: per-block sums ----------------
__global__ __launch_bounds__(256) void reduce_kernel(const int* __restrict__ counts,
                                                     int* __restrict__ block_sums) {
    __shared__ int lsum[4];
    int tid = threadIdx.x;
    int gid = blockIdx.x * 256 + tid;
    int s = (gid < N_NODES) ? counts[gid] : 0;
#pragma unroll
    for (int off = 32; off; off >>= 1) s += __shfl_down(s, off);
    if ((tid & 63) == 0) lsum[tid >> 6] = s;
    __syncthreads();
    if (tid == 0) block_sums[blockIdx.x] = lsum[0] + lsum[1] + lsum[2] + lsum[3];
}

// ---------------- scan phase 2 (merged) ----------------
__global__ __launch_bounds__(256) void scan_final(const int* __restrict__ counts,
                                                  const int* __restrict__ block_sums,
                                                  int* __restrict__ row_start) {
    __shared__ int sh[256];
    __shared__ int bs[256];
    int tid = threadIdx.x;
    int gid = blockIdx.x * 256 + tid;
    sh[tid] = (gid < N_NODES) ? counts[gid] : 0;
    bs[tid] = (tid < SCAN_NB) ? block_sums[tid] : 0;
    __syncthreads();
    for (int off = 1; off < 256; off <<= 1) {
        int t1 = (tid >= off) ? sh[tid - off] : 0;
        int t2 = (tid >= off) ? bs[tid - off] : 0;
        __syncthreads();
        sh[tid] += t1;
        bs[tid] += t2;
        __syncthreads();
    }
    int boff = (blockIdx.x == 0) ? 0 : bs[blockIdx.x - 1];
    int excl = (tid == 0) ? 0 : sh[tid - 1];
    if (gid < N_NODES) row_start[gid] = boff + excl;
    if (gid == 0) row_start[N_NODES] = E_EDGES;
}

// ---------------- CSR fill — no atomics ----------------
__global__ void fill_kernel(const int* __restrict__ src, const int* __restrict__ dst,
                            const float* __restrict__ w, const int* __restrict__ pos,
                            const int* __restrict__ row_start,
                            int2* __restrict__ csr_ew) {
    int e = blockIdx.x * blockDim.x + threadIdx.x;
    if (e >= E_EDGES) return;
    int d = dst[e];
    int idx = row_start[d] + pos[e];
    int2 rec;
    rec.x = src[e];
    rec.y = __float_as_int(w[e]);
    csr_ew[idx] = rec;
}

// ---------------- gather: 16 lanes/node, 2-edge unroll ----------------
__global__ __launch_bounds__(256) void gather_kernel(const u16* __restrict__ vbf,
                                                     const int* __restrict__ row_start,
                                                     const int2* __restrict__ csr_ew,
                                                     const float* __restrict__ eps_p,
                                                     u16* __restrict__ vagg) {
    int node = blockIdx.x * 16 + (threadIdx.x >> 4);
    if (node >= N_NODES) return;
    int c8 = (threadIdx.x & 15) << 3;
    int beg = row_start[node];
    int end = row_start[node + 1];
    float a[8] = {};
    int j = beg;
    for (; j + 1 < end; j += 2) {
        int2 e0 = csr_ew[j];
        int2 e1 = csr_ew[j + 1];
        float w0 = __int_as_float(e0.y);
        float w1 = __int_as_float(e1.y);
        float4 r0 = *(const float4*)(vbf + (size_t)e0.x * D_INF + c8);
        float4 r1 = *(const float4*)(vbf + (size_t)e1.x * D_INF + c8);
        const u16* p0 = (const u16*)&r0;
        const u16* p1 = (const u16*)&r1;
#pragma unroll
        for (int t = 0; t < 8; ++t) a[t] += w0 * bf2f(p0[t]);
#pragma unroll
        for (int t = 0; t < 8; ++t) a[t] += w1 * bf2f(p1[t]);
    }
    if (j < end) {
        int2 e0 = csr_ew[j];
        float w0 = __int_as_float(e0.y);
        float4 r0 = *(const float4*)(vbf + (size_t)e0.x * D_INF + c8);
        const u16* p0 = (const u16*)&r0;
#pragma unroll
        for (int t = 0; t < 8; ++t) a[t] += w0 * bf2f(p0[t]);
    }
    float e = eps_p[0];
    float4 rn = *(const float4*)(vbf + (size_t)node * D_INF + c8);
    const u16* pn = (const u16*)&rn;
    u16 o[8];
#pragma unroll
    for (int t = 0; t < 8; ++t) o[t] = f2bf(a[t] + e * bf2f(pn[t]));
    *(float4*)(vagg + (size_t)node * D_INF + c8) = *(const float4*)o;
}

// ---------------- stats GEMM1: x1 partial sums/squares ONLY (no x1 write) ----------
// 256x128 tile, gload_lds staging (proven R3/R4/R6 structure), no C epilogue.
// MFMA chain per output element is IDENTICAL to fused_mlp's recompute (same
// ks=0..3 K-order, same bf16 inputs) -> stats exactly consistent.
__global__ __launch_bounds__(512) void stats_gemm1(
        const u16* __restrict__ A, const u16* __restrict__ Bt,
        const float* __restrict__ bias,
        float* __restrict__ psum, float* __restrict__ psq, int M) {
    __shared__ __align__(16) char smem[24576];
    u16* As = (u16*)smem;              // [256][32] u16, src slot-swz ^(row&3)
    u16* Bs = (u16*)(smem + 16384);    // [128][32] u16
    const int bm = blockIdx.y * 256;
    const int bn = blockIdx.x * 128;
    const int tid = threadIdx.x;
    const int wave = tid >> 6, lane = tid & 63;
    const int wr = wave >> 1, wc = wave & 1;
    const int wm = wr * 64, wn = wc * 64;
    const int lm = lane & 15, quad = lane >> 4;
    floatx4 acc[4][4] = {};
    for (int ks = 0; ks < 4; ++ks) {
        const int k0 = ks << 5;
        {
            const int sub = lane >> 2, s = lane & 3;
#pragma unroll
            for (int t = 0; t < 3; ++t) {
                int ch = wave * 3 + t;
                if (ch < 16) {
                    int row = ch * 16 + sub;
                    int grow = bm + row; if (grow > M - 1) grow = M - 1;
                    int ss = s ^ (row & 3);
                    __builtin_amdgcn_global_load_lds(
                        (gas_t*)(A + (size_t)grow * 128 + k0 + ss * 8),
                        (las_t*)(As + row * 32 + s * 8), 16, 0, 0);
                } else {
                    int row = (ch - 16) * 16 + sub;
                    int ss = s ^ (row & 3);
                    __builtin_amdgcn_global_load_lds(
                        (gas_t*)(Bt + (size_t)(bn + row) * 128 + k0 + ss * 8),
                        (las_t*)(Bs + row * 32 + s * 8), 16, 0, 0);
                }
            }
        }
        __syncthreads();
        short8 af[4], bfr[4];
#pragma unroll
        for (int i = 0; i < 4; ++i) {
            int row = wm + i * 16 + lm;
            af[i] = *(const short8*)&As[row * 32 + ((quad ^ (row & 3)) * 8)];
        }
#pragma unroll
        for (int j = 0; j < 4; ++j) {
            int row = wn + j * 16 + lm;
            bfr[j] = *(const short8*)&Bs[row * 32 + ((quad ^ (row & 3)) * 8)];
        }
#pragma unroll
        for (int i = 0; i < 4; ++i)
#pragma unroll
            for (int j = 0; j < 4; ++j)
                acc[i][j] = __builtin_amdgcn_mfma_f32_16x16x32_bf16(af[i], bfr[j], acc[i][j], 0, 0, 0);
        __syncthreads();
    }
    float* redS = (float*)smem;
    float* redQ = redS + 128;
    if (tid < 128) { redS[tid] = 0.f; redQ[tid] = 0.f; }
    __syncthreads();
#pragma unroll
    for (int j = 0; j < 4; ++j) {
        int cl = wn + j * 16 + lm;
        float bj = bias[bn + cl];
        float s = 0.f, q = 0.f;
#pragma unroll
        for (int i = 0; i < 4; ++i) {
            int row0 = bm + wm + i * 16 + quad * 4;
#pragma unroll
            for (int r = 0; r < 4; ++r)
                if (row0 + r < M) { float x = acc[i][j][r] + bj; s += x; q += x * x; }
        }
        s += __shfl_xor(s, 16); q += __shfl_xor(q, 16);
        s += __shfl_xor(s, 32); q += __shfl_xor(q, 32);
        if (quad == 0) { atomicAdd(&redS[cl], s); atomicAdd(&redQ[cl], q); }
    }
    __syncthreads();
    if (tid < 128) {
        psum[(size_t)blockIdx.y * 512 + bn + tid] = redS[tid];
        psq [(size_t)blockIdx.y * 512 + bn + tid] = redQ[tid];
    }
}

// ---------------- fused v2: recompute-GEMM1 + BN1 + ReLU -> h(LDS, 2 half-K passes)
//                  -> GEMM2 + BN2 partials.  48 KB LDS -> 3 blocks/CU.
// 64 rows/block, 512 thr (8 waves = 2x4).
// Phase 1 LDS: As [64][128]u16 (16K) + W1s [512][32]u16 (32K), 4 K-windows of 32.
// Phase 2 LDS: W2s [128][64]u16 (16K, over As) + hs [64][256]u16 (32K, over W1s).
// GEMM2 K split: pass p consumes acc1 j=p*4..p*4+3; k' = wc*64+j*16+lm maps to
// global k = wc*128 + p*64 + j*16 + lm; W2s window w sources W2t k = w*128+p*64.
// K-order permutation only reorders fp accumulation (within bf16 tolerance).
__global__ __launch_bounds__(512, 4) void fused_mlp(
        const u16* __restrict__ vagg, const u16* __restrict__ W1t,
        const u16* __restrict__ W2t,
        const float* __restrict__ b1, const float* __restrict__ scale1,
        const float* __restrict__ shift1, const float* __restrict__ b2,
        u16* __restrict__ x2, float* __restrict__ psum, float* __restrict__ psq,
        int M) {
    __shared__ __align__(16) char smem[49152];
    u16* As  = (u16*)smem;                 // [64][128] u16
    u16* W1s = (u16*)(smem + 16384);       // [512][32] u16
    u16* W2s = (u16*)smem;                 // [128][64] u16 (phase 2)
    u16* hs  = (u16*)(smem + 16384);       // [64][256] u16 (phase 2)
    const int bm = blockIdx.x * 64;
    const int tid = threadIdx.x;
    const int wave = tid >> 6, lane = tid & 63;
    const int wr = wave >> 2, wc = wave & 3;     // 2 row x 4 col wave groups
    const int wm = wr * 32;
    const int wn1 = wc * 128;                    // GEMM1 col span 128
    const int wn2 = wc * 32;                     // GEMM2 col span 32
    const int lm = lane & 15, quad = lane >> 4;

    floatx4 acc1[2][8] = {};
    floatx4 acc2[2][2] = {};

    auto stage_w1 = [&](int win) {               // [512][32]u16 = 32 KB, 4 rounds
#pragma unroll
        for (int u = 0; u < 4; ++u) {
            int c = tid + u * 512;
            int col = c >> 2, s = c & 3;
            __builtin_amdgcn_global_load_lds(
                (gas_t*)(W1t + (size_t)col * 128 + win * 32 + ((s ^ (col & 3)) * 8)),
                (las_t*)(W1s + col * 32 + s * 8), 16, 0, 0);
        }
    };
    auto stage_w2 = [&](int p, int w) {          // [128][64]u16 = 16 KB, 2 rounds
#pragma unroll
        for (int u = 0; u < 2; ++u) {
            int c = tid + u * 512;
            int n = c >> 3, s = c & 7;
            __builtin_amdgcn_global_load_lds(
                (gas_t*)(W2t + (size_t)n * 512 + w * 128 + p * 64 + ((s ^ (n & 7)) * 8)),
                (las_t*)(W2s + n * 64 + s * 8), 16, 0, 0);
        }
    };
    auto compute1 = [&](int win) {               // one K=32 step at k = win*32
        short8 a[2], b[8];
#pragma unroll
        for (int i = 0; i < 2; ++i) {
            int row = wm + i * 16 + lm;
            a[i] = *(const short8*)&As[row * 128 + (((win * 4 + quad) ^ (row & 7)) * 8)];
        }
#pragma unroll
        for (int j = 0; j < 8; ++j) {
            int col = wn1 + j * 16 + lm;
            b[j] = *(const short8*)&W1s[col * 32 + ((quad ^ (col & 3)) * 8)];
        }
#pragma unroll
        for (int i = 0; i < 2; ++i)
#pragma unroll
            for (int j = 0; j < 8; ++j)
                acc1[i][j] = __builtin_amdgcn_mfma_f32_16x16x32_bf16(a[i], b[j], acc1[i][j], 0, 0, 0);
    };
    auto compute2 = [&](int w, int ks) {         // hs k'-window w*64, kstep ks
        short8 a[2], b[2];
#pragma unroll
        for (int i = 0; i < 2; ++i) {
            int row = wm + i * 16 + lm;
            a[i] = *(const short8*)&hs[row * 256 + (((w * 8 + ks * 4 + quad) ^ (row & 7)) * 8)];
        }
#pragma unroll
        for (int j = 0; j < 2; ++j) {
            int n = wn2 + j * 16 + lm;
            b[j] = *(const short8*)&W2s[n * 64 + (((ks * 4 + quad) ^ (n & 7)) * 8)];
        }
#pragma unroll
        for (int i = 0; i < 2; ++i)
#pragma unroll
            for (int j = 0; j < 2; ++j)
                acc2[i][j] = __builtin_amdgcn_mfma_f32_16x16x32_bf16(a[i], b[j], acc2[i][j], 0, 0, 0);
    };
    auto store_h = [&](int p) {                  // BN1+ReLU on acc1 j=p*4..p*4+3 -> hs
        float hsc[4], hsh[4];
#pragma unroll
        for (int j = 0; j < 4; ++j) {
            int col = wn1 + (p * 4 + j) * 16 + lm;
            float sc = scale1[col];
            hsc[j] = sc;
            hsh[j] = shift1[col] + sc * b1[col];
        }
#pragma unroll
        for (int i = 0; i < 2; ++i)
#pragma unroll
            for (int j = 0; j < 4; ++j)
#pragma unroll
                for (int r = 0; r < 4; ++r) {
                    int row = wm + i * 16 + quad * 4 + r;
                    int kp = wc * 64 + j * 16 + lm;   // k' in [0,256)
                    float hv = fmaxf(0.f, acc1[i][p * 4 + j][r] * hsc[j] + hsh[j]);
                    hs[row * 256 + (((kp >> 3) ^ (row & 7)) * 8) + (kp & 7)] = f2bf(hv);
                }
    };

    // ---- GEMM1: stage vagg tile + 4 W1 K-windows ----
#pragma unroll
    for (int u = 0; u < 2; ++u) {
        int c = tid + u * 512;
        int row = c >> 4, s = c & 15;
        int grow = bm + row; if (grow > M - 1) grow = M - 1;
        __builtin_amdgcn_global_load_lds(
            (gas_t*)(vagg + (size_t)grow * 128 + ((s ^ (row & 7)) * 8)),
            (las_t*)(As + row * 128 + s * 8), 16, 0, 0);
    }
    stage_w1(0);
    __syncthreads();
    compute1(0);
    __syncthreads();
    stage_w1(1);
    __syncthreads();
    compute1(1);
    __syncthreads();
    stage_w1(2);
    __syncthreads();
    compute1(2);
    __syncthreads();
    stage_w1(3);
    __syncthreads();
    compute1(3);
    __syncthreads();                  // all reads of As / W1s done

    // ---- GEMM2: two half-K passes, 4 W2 windows each ----
#pragma unroll
    for (int p = 0; p < 2; ++p) {
        stage_w2(p, 0);               // issue early; hides under store_h
        store_h(p);
        __syncthreads();              // hs visible + W2s(p,0) staged
#pragma unroll
        for (int w = 0; w < 4; ++w) {
            compute2(w, 0); compute2(w, 1);
            __syncthreads();
            if (w < 3) { stage_w2(p, w + 1); __syncthreads(); }
        }
    }

    // ---- BN2 partials ----
    float* redS = (float*)smem;
    float* redQ = redS + 128;
    if (tid < 128) { redS[tid] = 0.f; redQ[tid] = 0.f; }
    __syncthreads();
    float bj2[2];
#pragma unroll
    for (int j = 0; j < 2; ++j) {
        int cl = wn2 + j * 16 + lm;
        bj2[j] = b2[cl];
        float s = 0.f, q = 0.f;
#pragma unroll
        for (int i = 0; i < 2; ++i) {
            int row0 = bm + wm + i * 16 + quad * 4;
#pragma unroll
            for (int r = 0; r < 4; ++r)
                if (row0 + r < M) { float x = acc2[i][j][r] + bj2[j]; s += x; q += x * x; }
        }
        s += __shfl_xor(s, 16); q += __shfl_xor(q, 16);
        s += __shfl_xor(s, 32); q += __shfl_xor(q, 32);
        if (quad == 0) { atomicAdd(&redS[cl], s); atomicAdd(&redQ[cl], q); }
    }
    __syncthreads();
    if (tid < 128) {
        psum[(size_t)blockIdx.x * 128 + tid] = redS[tid];
        psq [(size_t)blockIdx.x * 128 + tid] = redQ[tid];
    }
    __syncthreads();                  // redS reads done before obuf overwrite

    // ---- coalesced bf16 x2 write via obuf [64][132] f32 ----
    float* obuf = (float*)smem;
#pragma unroll
    for (int i = 0; i < 2; ++i)
#pragma unroll
        for (int j = 0; j < 2; ++j)
#pragma unroll
            for (int r = 0; r < 4; ++r) {
                int row = wm + i * 16 + quad * 4 + r;
                int col = wn2 + j * 16 + lm;
                obuf[row * 132 + col] = acc2[i][j][r] + bj2[j];
            }
    __syncthreads();
    {
        int row = tid >> 3, seg = (tid & 7) * 16;
        int grow = bm + row;
        if (grow < M) {
            u16 ob[16];
#pragma unroll
            for (int t = 0; t < 4; ++t) {
                float4 f = *(float4*)&obuf[row * 132 + seg + t * 4];
                ob[t * 4 + 0] = f2bf(f.x);
                ob[t * 4 + 1] = f2bf(f.y);
                ob[t * 4 + 2] = f2bf(f.z);
                ob[t * 4 + 3] = f2bf(f.w);
            }
            u16* dp = x2 + (size_t)grow * 128 + seg;
            *(float4*)dp       = *(float4*)ob;
            *(float4*)(dp + 8) = *(float4*)(ob + 8);
        }
    }
}

// ---------------- BN finalize (parallel reduce of per-block partials) ----------------
__global__ __launch_bounds__(1024) void bn_finalize_kernel(
        const float* __restrict__ psum, const float* __restrict__ psq,
        const float* __restrict__ gamma, const float* __restrict__ beta,
        float* __restrict__ scale, float* __restrict__ shift,
        int nblocks, int Ncols, float inv_n) {
    __shared__ float shS[16][64];
    __shared__ float shQ[16][64];
    const int tx = threadIdx.x;
    const int ty = threadIdx.y;
    const int c = blockIdx.x * 64 + tx;
    float s = 0.f, q = 0.f;
    for (int b = ty; b < nblocks; b += 16) {
        s += psum[(size_t)b * Ncols + c];
        q += psq [(size_t)b * Ncols + c];
    }
    shS[ty][tx] = s;
    shQ[ty][tx] = q;
    __syncthreads();
    if (ty == 0) {
        float S = 0.f, Q = 0.f;
#pragma unroll
        for (int r = 0; r < 16; ++r) { S += shS[r][tx]; Q += shQ[r][tx]; }
        float m = S * inv_n;
        float var = Q * inv_n - m * m;
        float rs = rsqrtf(var + 1e-5f);
        float sc = gamma[c] * rs;
        scale[c] = sc;
        shift[c] = beta[c] - sc * m;
    }
}

// ---------------- BN2 apply + ReLU: x2 bf16 -> d_out fp32 ----------------
__global__ void bn2_apply_kernel(const u16* __restrict__ X, float* __restrict__ Y,
                                 const float* __restrict__ scale,
                                 const float* __restrict__ shift, int n8) {
    int i = blockIdx.x * blockDim.x + threadIdx.x;
    if (i >= n8) return;
    int c = (i & 15) << 3;
    float4 raw = ((const float4*)X)[i];
    const u16* xb = (const u16*)&raw;
    float4 sc0 = *(const float4*)(scale + c);
    float4 sc1 = *(const float4*)(scale + c + 4);
    float4 sh0 = *(const float4*)(shift + c);
    float4 sh1 = *(const float4*)(shift + c + 4);
    float4 y0, y1;
    y0.x = fmaxf(0.f, bf2f(xb[0]) * sc0.x + sh0.x);
    y0.y = fmaxf(0.f, bf2f(xb[1]) * sc0.y + sh0.y);
    y0.z = fmaxf(0.f, bf2f(xb[2]) * sc0.z + sh0.z);
    y0.w = fmaxf(0.f, bf2f(xb[3]) * sc0.w + sh0.w);
    y1.x = fmaxf(0.f, bf2f(xb[4]) * sc1.x + sh1.x);
    y1.y = fmaxf(0.f, bf2f(xb[5]) * sc1.y + sh1.y);
    y1.z = fmaxf(0.f, bf2f(xb[6]) * sc1.z + sh1.z);
    y1.w = fmaxf(0.f, bf2f(xb[7]) * sc1.w + sh1.w);
    ((float4*)Y)[i * 2]     = y0;
    ((float4*)Y)[i * 2 + 1] = y1;
}

extern "C" void kernel_launch(void* const* d_in, const int* in_sizes, int n_in,
                              void* d_out, int out_size, void* d_ws, size_t ws_size,
                              hipStream_t stream) {
    const float* v    = (const float*)d_in[0];
    const int* src    = (const int*)d_in[1];
    const int* dst    = (const int*)d_in[2];
    const float* ew   = (const float*)d_in[3];
    const float* eps  = (const float*)d_in[4];
    const float* W1   = (const float*)d_in[5];
    const float* b1   = (const float*)d_in[6];
    const float* g1   = (const float*)d_in[7];
    const float* be1  = (const float*)d_in[8];
    const float* W2   = (const float*)d_in[9];
    const float* b2   = (const float*)d_in[10];
    const float* g2   = (const float*)d_in[11];
    const float* be2  = (const float*)d_in[12];
    float* out = (float*)d_out;

    // ---- workspace layout (bytes) ----
    char* base = (char*)d_ws;
    u16* vbf  = (u16*)(base + 51200000ull);        // [N,128] bf16
    u16* vagg = (u16*)(base + 64000000ull);        // [N,128] bf16
    u16* x2   = (u16*)(base + 76800000ull);        // [N,128] bf16 raw pre-BN2
    u16* W1t  = (u16*)(base + 89600000ull);        // 512x128 bf16
    u16* W2t  = (u16*)(base + 89731072ull);        // 128x512 bf16
    float* psum   = (float*)(base + 89862144ull);  // [196][512] then [782][128]
    float* psq    = (float*)(base + 90663168ull);  // same
    float* scale1 = (float*)(base + 91464192ull);  // 512
    float* shift1 = scale1 + 512;
    float* scale2 = shift1 + 512;
    float* shift2 = scale2 + 128;
    int* counts     = (int*)(shift2 + 128);        // 50,000
    int* row_start  = counts + 50000;              // 50,001 (+pad 3)
    int* pos        = row_start + 50004;           // 800,000
    int2* csr_ew    = (int2*)(pos + 800000);       // 800,000 * 8 B
    int* block_sums = (int*)(csr_ew + 800000);     // 256

    hipMemsetAsync(counts, 0, (size_t)50000 * sizeof(int), stream);

    // merged prep (hist first | cast | W1^T | W2^T) + CSR build + gather
    prep_all_kernel<<<PREP_ALL_NB, 256, 0, stream>>>(v, W1, W2, dst, vbf, W1t, W2t,
                                                     counts, pos);
    reduce_kernel<<<SCAN_NB, 256, 0, stream>>>(counts, block_sums);
    scan_final<<<SCAN_NB, 256, 0, stream>>>(counts, block_sums, row_start);
    fill_kernel<<<(E_EDGES + 255) / 256, 256, 0, stream>>>(src, dst, ew, pos, row_start, csr_ew);
    gather_kernel<<<(N_NODES + 15) / 16, 256, 0, stream>>>(vbf, row_start, csr_ew, eps, vagg);

    // pass 1: BN1 statistics only (no x1 materialization)
    {
        dim3 grid(D_HIDF / 128, M1BLKS);
        stats_gemm1<<<grid, 512, 0, stream>>>(vagg, W1t, b1, psum, psq, N_NODES);
    }
    bn_finalize_kernel<<<D_HIDF / 64, dim3(64, 16), 0, stream>>>(
        psum, psq, g1, be1, scale1, shift1, M1BLKS, D_HIDF, 1.0f / N_NODES);

    // pass 2: fused recompute-GEMM1 + BN1 + ReLU (h in LDS) + GEMM2 + BN2 partials
    fused_mlp<<<FBLKS, 512, 0, stream>>>(vagg, W1t, W2t, b1, scale1, shift1, b2,
                                         x2, psum, psq, N_NODES);
    bn_finalize_kernel<<<D_OUTF / 64, dim3(64, 16), 0, stream>>>(
        psum, psq, g2, be2, scale2, shift2, FBLKS, D_OUTF, 1.0f / N_NODES);

    // BN2 apply + ReLU: x2 (bf16) -> d_out (fp32)
    {
        int n8 = N_NODES * D_OUTF / 8;
        bn2_apply_kernel<<<(n8 + 255) / 256, 256, 0, stream>>>(x2, out, scale2, shift2, n8);
    }
}